// Round 2
// baseline (5313.182 us; speedup 1.0000x reference)
//
#include <hip/hip_runtime.h>

namespace {
constexpr int B = 4, C = 64, H = 512, W = 512;
constexpr int HW = H * W;
constexpr float EPS = 1e-5f;

// ---------------- fast path: transposed accumulator ----------------

__global__ __launch_bounds__(256) void conv_scatter_T_kernel(
    const float* __restrict__ x, const float* __restrict__ wmat,
    const float* __restrict__ bias, float* __restrict__ wsT,
    float* __restrict__ offset, float* __restrict__ dest,
    float* __restrict__ aa)
{
    __shared__ float wsh[3 * C];
    int t = threadIdx.x;
    if (t < 3 * C) wsh[t] = wmat[t];
    __syncthreads();

    int gid = blockIdx.x * 256 + t;       // pixel id within B*HW (grid exact)
    int b = gid >> 18;                    // / HW  (HW = 2^18)
    int p = gid & (HW - 1);
    int hh = p >> 9, ww = p & (W - 1);

    const float* xb = x + (size_t)b * C * HW + p;
    float xv[C];
    float acc0 = 0.f, acc1 = 0.f, acc2 = 0.f;
#pragma unroll
    for (int c = 0; c < C; ++c) {
        float v = xb[(size_t)c * HW];     // coalesced across lanes per c
        xv[c] = v;
        acc0 = fmaf(v, wsh[c], acc0);
        acc1 = fmaf(v, wsh[C + c], acc1);
        acc2 = fmaf(v, wsh[2 * C + c], acc2);
    }
    acc0 += bias[0];
    acc1 += bias[1];
    acc2 += bias[2];

    float off_y = acc0 * (float)H;        // DOWNSAMPLE = 1.0
    float off_x = acc1 * (float)W;
    float att = expf(acc2);

    int dy = (int)rintf((float)hh + off_y);   // RNE == jnp.round
    dy = min(max(dy, 0), H - 1);
    int dx = (int)rintf((float)ww + off_x);
    dx = min(max(dx, 0), W - 1);
    int idx = dy * W + dx;

    size_t ob = (size_t)b * 2 * HW;
    offset[ob + p]      = off_y;
    offset[ob + HW + p] = off_x;
    dest[ob + p]      = (float)dy;
    dest[ob + HW + p] = (float)dx;

    atomicAdd(&aa[b * HW + idx], att);
    // channel-contiguous accumulator: 64 adds -> 4 consecutive cache lines
    float* outp = wsT + ((size_t)(b * HW) + idx) * C;
#pragma unroll
    for (int c = 0; c < C; ++c) {
        atomicAdd(&outp[c], xv[c] * att);
    }
}

// wsT [B,HW,C] -> out [B,C,HW], divided by (aa+EPS). 64-pixel x 64-ch tiles.
__global__ __launch_bounds__(256) void transpose_norm_kernel(
    const float* __restrict__ wsT, const float* __restrict__ aa,
    float* __restrict__ out)
{
    __shared__ float tile[64][65];
    __shared__ float rinv[64];
    int blk = blockIdx.x;                 // B*HW/64 = 16384 blocks
    int b = blk >> 12;                    // 4096 tiles per image
    int p0 = (blk & 4095) * 64;
    int t = threadIdx.x;

    if (t < 64) rinv[t] = 1.0f / (aa[(size_t)b * HW + p0 + t] + EPS);
    const float* src = wsT + ((size_t)b * HW + p0) * C;
#pragma unroll
    for (int i = 0; i < 16; ++i) {
        int e = i * 256 + t;              // [pixel r][channel c], coalesced 1KB
        tile[e >> 6][e & 63] = src[e];
    }
    __syncthreads();
    float* dst = out + (size_t)b * C * HW + p0;
#pragma unroll
    for (int i = 0; i < 16; ++i) {
        int f = i * 256 + t;
        int c = f >> 6, r = f & 63;       // per-wave: c fixed, r=lane -> coalesced
        dst[(size_t)c * HW + r] = tile[r][c] * rinv[r];
    }
}

// ---------------- fallback path (R1, needs only 4 MB ws) ----------------

__global__ __launch_bounds__(256) void init_aa_kernel(float* __restrict__ aa) {
    int i = blockIdx.x * 256 + threadIdx.x;
    aa[i] = EPS;
}

__global__ __launch_bounds__(256) void conv_scatter_kernel(
    const float* __restrict__ x, const float* __restrict__ wmat,
    const float* __restrict__ bias, float* __restrict__ out,
    float* __restrict__ offset, float* __restrict__ dest,
    float* __restrict__ aa)
{
    __shared__ float wsh[3 * C];
    int t = threadIdx.x;
    if (t < 3 * C) wsh[t] = wmat[t];
    __syncthreads();

    int gid = blockIdx.x * 256 + t;
    int b = gid >> 18;
    int p = gid & (HW - 1);
    int hh = p >> 9, ww = p & (W - 1);

    const float* xb = x + (size_t)b * C * HW + p;
    float xv[C];
    float acc0 = 0.f, acc1 = 0.f, acc2 = 0.f;
#pragma unroll
    for (int c = 0; c < C; ++c) {
        float v = xb[(size_t)c * HW];
        xv[c] = v;
        acc0 = fmaf(v, wsh[c], acc0);
        acc1 = fmaf(v, wsh[C + c], acc1);
        acc2 = fmaf(v, wsh[2 * C + c], acc2);
    }
    acc0 += bias[0];
    acc1 += bias[1];
    acc2 += bias[2];

    float off_y = acc0 * (float)H;
    float off_x = acc1 * (float)W;
    float att = expf(acc2);

    int dy = (int)rintf((float)hh + off_y);
    dy = min(max(dy, 0), H - 1);
    int dx = (int)rintf((float)ww + off_x);
    dx = min(max(dx, 0), W - 1);
    int idx = dy * W + dx;

    size_t ob = (size_t)b * 2 * HW;
    offset[ob + p]      = off_y;
    offset[ob + HW + p] = off_x;
    dest[ob + p]      = (float)dy;
    dest[ob + HW + p] = (float)dx;

    atomicAdd(&aa[b * HW + idx], att);
    float* outp = out + (size_t)b * C * HW + idx;
#pragma unroll
    for (int c = 0; c < C; ++c) {
        atomicAdd(&outp[(size_t)c * HW], xv[c] * att);
    }
}

__global__ __launch_bounds__(256) void normalize_kernel(
    float* __restrict__ out, const float* __restrict__ aa)
{
    int i4 = blockIdx.x * 256 + threadIdx.x;
    size_t e = (size_t)i4 * 4;
    int b = (int)(e / ((size_t)C * HW));
    int p = (int)(e & (size_t)(HW - 1));
    float4 v = *reinterpret_cast<float4*>(out + e);
    const float4 a = *reinterpret_cast<const float4*>(aa + (size_t)b * HW + p);
    v.x /= a.x; v.y /= a.y; v.z /= a.z; v.w /= a.w;
    *reinterpret_cast<float4*>(out + e) = v;
}
} // namespace

extern "C" void kernel_launch(void* const* d_in, const int* in_sizes, int n_in,
                              void* d_out, int out_size, void* d_ws, size_t ws_size,
                              hipStream_t stream) {
    const float* x    = (const float*)d_in[0];
    const float* wmat = (const float*)d_in[1];
    const float* bias = (const float*)d_in[2];

    float* out    = (float*)d_out;                    // [B,C,H,W]
    float* offset = out + (size_t)B * C * HW;         // [B,2,H,W]
    float* dest   = offset + (size_t)B * 2 * HW;      // [B,2,H,W]

    const size_t wsT_elems = (size_t)B * HW * C;      // 64M floats = 256 MB
    const size_t aa_elems  = (size_t)B * HW;          // 1M floats = 4 MB
    const size_t need = (wsT_elems + aa_elems) * sizeof(float);

    if (ws_size >= need) {
        float* wsT = (float*)d_ws;                    // [B,HW,C]
        float* aa  = wsT + wsT_elems;                 // [B,HW]
        hipMemsetAsync(d_ws, 0, need, stream);        // zero wsT + aa (EPS added in K2)
        conv_scatter_T_kernel<<<B * HW / 256, 256, 0, stream>>>(
            x, wmat, bias, wsT, offset, dest, aa);
        transpose_norm_kernel<<<B * HW / 64, 256, 0, stream>>>(wsT, aa, out);
    } else {
        // fallback: R1 path, accumulate directly in d_out (4 MB ws)
        float* aa = (float*)d_ws;
        hipMemsetAsync(out, 0, (size_t)B * C * HW * sizeof(float), stream);
        init_aa_kernel<<<B * HW / 256, 256, 0, stream>>>(aa);
        conv_scatter_kernel<<<B * HW / 256, 256, 0, stream>>>(
            x, wmat, bias, out, offset, dest, aa);
        normalize_kernel<<<(B * (size_t)C * HW / 4) / 256, 256, 0, stream>>>(out, aa);
    }
}

// Round 3
// 785.897 us; speedup vs baseline: 6.7607x; 6.7607x over previous
//
#include <hip/hip_runtime.h>

namespace {
constexpr int B = 4, C = 64, H = 512, W = 512;
constexpr int HW = H * W;                 // 2^18
constexpr int ND = B * HW;                // 2^20 source pixels == destinations
constexpr float EPS = 1e-5f;
constexpr int KT = 64;                    // heavy-destination threshold
constexpr int HEAVY_CAP = 16384;          // > ND/(KT+1) = 16128, proof-bounded

__device__ __forceinline__ float bf16_lo(unsigned int u) {
    return __uint_as_float(u << 16);
}
__device__ __forceinline__ float bf16_hi(unsigned int u) {
    return __uint_as_float(u & 0xffff0000u);
}
__device__ __forceinline__ unsigned int pack_bf16(float a, float b) {
    // RNE round f32->bf16, b in high half
    unsigned int ua = __float_as_uint(a), ub = __float_as_uint(b);
    ua = (ua + 0x7fffu + ((ua >> 16) & 1u)) >> 16;
    ub = (ub + 0x7fffu + ((ub >> 16) & 1u)) >> 16;
    return ua | (ub << 16);
}

// ---------------- fast path: sort + gather (no accumulator atomics) --------

__global__ __launch_bounds__(256) void conv_kernel(
    const float* __restrict__ x, const float* __restrict__ wmat,
    const float* __restrict__ bias,
    uint4* __restrict__ xwT, float* __restrict__ att_a,
    int* __restrict__ idx_a, int* __restrict__ count,
    float* __restrict__ offset, float* __restrict__ dest)
{
    __shared__ float wsh[3 * C];
    int t = threadIdx.x;
    if (t < 3 * C) wsh[t] = wmat[t];
    __syncthreads();

    int gid = blockIdx.x * 256 + t;       // global source id (b<<18 | p)
    int b = gid >> 18;
    int p = gid & (HW - 1);
    int hh = p >> 9, ww = p & (W - 1);

    const float* xb = x + (size_t)b * C * HW + p;
    float xv[C];
    float acc0 = 0.f, acc1 = 0.f, acc2 = 0.f;
#pragma unroll
    for (int c = 0; c < C; ++c) {
        float v = xb[(size_t)c * HW];     // coalesced per c
        xv[c] = v;
        acc0 = fmaf(v, wsh[c], acc0);
        acc1 = fmaf(v, wsh[C + c], acc1);
        acc2 = fmaf(v, wsh[2 * C + c], acc2);
    }
    acc0 += bias[0]; acc1 += bias[1]; acc2 += bias[2];

    float off_y = acc0 * (float)H;        // DOWNSAMPLE = 1.0
    float off_x = acc1 * (float)W;
    float att = expf(acc2);

    int dy = (int)rintf((float)hh + off_y);   // RNE == jnp.round
    dy = min(max(dy, 0), H - 1);
    int dx = (int)rintf((float)ww + off_x);
    dx = min(max(dx, 0), W - 1);
    int idx = dy * W + dx;

    size_t ob = (size_t)b * 2 * HW;
    offset[ob + p]      = off_y;
    offset[ob + HW + p] = off_x;
    dest[ob + p]      = (float)dy;
    dest[ob + HW + p] = (float)dx;

    att_a[gid] = att;
    idx_a[gid] = idx;
    atomicAdd(&count[(b << 18) | idx], 1);  // histogram: 1 small atomic/thread

    // bf16-packed, att-premultiplied feature row: 128B per source
    uint4* row = xwT + (size_t)gid * 8;
#pragma unroll
    for (int j = 0; j < 8; ++j) {
        uint4 v;
        v.x = pack_bf16(xv[j * 8 + 0] * att, xv[j * 8 + 1] * att);
        v.y = pack_bf16(xv[j * 8 + 2] * att, xv[j * 8 + 3] * att);
        v.z = pack_bf16(xv[j * 8 + 4] * att, xv[j * 8 + 5] * att);
        v.w = pack_bf16(xv[j * 8 + 6] * att, xv[j * 8 + 7] * att);
        row[j] = v;
    }
}

__global__ __launch_bounds__(256) void scan_alloc_kernel(
    const int* __restrict__ count, int* __restrict__ base,
    int* __restrict__ cursor, int* __restrict__ alloc)
{
    __shared__ int sd[256];
    __shared__ int blockBase;
    int t = threadIdx.x;
    int i = blockIdx.x * 256 + t;
    int c = count[i];
    sd[t] = c;
    __syncthreads();
#pragma unroll
    for (int off = 1; off < 256; off <<= 1) {     // Hillis-Steele inclusive
        int v = (t >= off) ? sd[t - off] : 0;
        __syncthreads();
        sd[t] += v;
        __syncthreads();
    }
    if (t == 255) blockBase = atomicAdd(alloc, sd[255]);
    __syncthreads();
    int bb = blockBase + sd[t] - c;               // exclusive within block
    base[i] = bb;
    cursor[i] = bb;
}

__global__ __launch_bounds__(256) void place_kernel(
    const int* __restrict__ idx_a, int* __restrict__ cursor,
    int* __restrict__ slist)
{
    int s = blockIdx.x * 256 + threadIdx.x;
    int d = (s & ~(HW - 1)) | idx_a[s];           // same-batch destination
    int pos = atomicAdd(&cursor[d], 1);
    slist[pos] = s;
}

__global__ __launch_bounds__(256) void gather_kernel(
    const uint4* __restrict__ xwT, const float* __restrict__ att_a,
    const int* __restrict__ count, const int* __restrict__ base,
    const int* __restrict__ slist, float* __restrict__ out,
    int* __restrict__ heavy, int* __restrict__ heavy_n)
{
    int d = blockIdx.x * 256 + threadIdx.x;
    int k = count[d];
    if (k > KT) {
        heavy[atomicAdd(heavy_n, 1)] = d;         // handled by heavy_kernel
        return;
    }
    float acc[C];
#pragma unroll
    for (int c = 0; c < C; ++c) acc[c] = 0.f;
    float asum = 0.f;
    int st = base[d];
    for (int i = 0; i < k; ++i) {
        int s = slist[st + i];
        asum += att_a[s];
        const uint4* row = xwT + (size_t)s * 8;   // 128B random-access record
#pragma unroll
        for (int j = 0; j < 8; ++j) {
            uint4 v = row[j];
            acc[j * 8 + 0] += bf16_lo(v.x); acc[j * 8 + 1] += bf16_hi(v.x);
            acc[j * 8 + 2] += bf16_lo(v.y); acc[j * 8 + 3] += bf16_hi(v.y);
            acc[j * 8 + 4] += bf16_lo(v.z); acc[j * 8 + 5] += bf16_hi(v.z);
            acc[j * 8 + 6] += bf16_lo(v.w); acc[j * 8 + 7] += bf16_hi(v.w);
        }
    }
    float rinv = 1.0f / (EPS + asum);
    int b = d >> 18, p = d & (HW - 1);
    float* op = out + (size_t)b * C * HW + p;
#pragma unroll
    for (int c = 0; c < C; ++c) op[(size_t)c * HW] = acc[c] * rinv;  // coalesced
}

__global__ __launch_bounds__(256) void heavy_kernel(
    const unsigned short* __restrict__ xwT16, const float* __restrict__ att_a,
    const int* __restrict__ count, const int* __restrict__ base,
    const int* __restrict__ slist, float* __restrict__ out,
    const int* __restrict__ heavy, const int* __restrict__ heavy_n)
{
    __shared__ float red[4][C];
    __shared__ float asums[4];
    int nh = *heavy_n;
    int wid = threadIdx.x >> 6, lane = threadIdx.x & 63;
    for (int hi = blockIdx.x; hi < nh; hi += gridDim.x) {
        int d = heavy[hi];
        int k = count[d], st = base[d];
        float acc = 0.f, asum = 0.f;
        for (int i = wid; i < k; i += 4) {        // 4 waves split the sources
            int s = slist[st + i];
            asum += att_a[s];
            unsigned short u = xwT16[(size_t)s * 64 + lane];  // coalesced 128B
            acc += __uint_as_float(((unsigned int)u) << 16);
        }
        red[wid][lane] = acc;
        if (lane == 0) asums[wid] = asum;
        __syncthreads();
        if (wid == 0) {
            float a = red[0][lane] + red[1][lane] + red[2][lane] + red[3][lane];
            float as = asums[0] + asums[1] + asums[2] + asums[3];
            int b = d >> 18, p = d & (HW - 1);
            out[(size_t)b * C * HW + (size_t)lane * HW + p] = a / (EPS + as);
        }
        __syncthreads();
    }
}

// ---------------- fallback path (R1, needs only 4 MB ws) ----------------

__global__ __launch_bounds__(256) void init_aa_kernel(float* __restrict__ aa) {
    int i = blockIdx.x * 256 + threadIdx.x;
    aa[i] = EPS;
}

__global__ __launch_bounds__(256) void conv_scatter_kernel(
    const float* __restrict__ x, const float* __restrict__ wmat,
    const float* __restrict__ bias, float* __restrict__ out,
    float* __restrict__ offset, float* __restrict__ dest,
    float* __restrict__ aa)
{
    __shared__ float wsh[3 * C];
    int t = threadIdx.x;
    if (t < 3 * C) wsh[t] = wmat[t];
    __syncthreads();

    int gid = blockIdx.x * 256 + t;
    int b = gid >> 18;
    int p = gid & (HW - 1);
    int hh = p >> 9, ww = p & (W - 1);

    const float* xb = x + (size_t)b * C * HW + p;
    float xv[C];
    float acc0 = 0.f, acc1 = 0.f, acc2 = 0.f;
#pragma unroll
    for (int c = 0; c < C; ++c) {
        float v = xb[(size_t)c * HW];
        xv[c] = v;
        acc0 = fmaf(v, wsh[c], acc0);
        acc1 = fmaf(v, wsh[C + c], acc1);
        acc2 = fmaf(v, wsh[2 * C + c], acc2);
    }
    acc0 += bias[0]; acc1 += bias[1]; acc2 += bias[2];

    float off_y = acc0 * (float)H;
    float off_x = acc1 * (float)W;
    float att = expf(acc2);

    int dy = (int)rintf((float)hh + off_y);
    dy = min(max(dy, 0), H - 1);
    int dx = (int)rintf((float)ww + off_x);
    dx = min(max(dx, 0), W - 1);
    int idx = dy * W + dx;

    size_t ob = (size_t)b * 2 * HW;
    offset[ob + p]      = off_y;
    offset[ob + HW + p] = off_x;
    dest[ob + p]      = (float)dy;
    dest[ob + HW + p] = (float)dx;

    atomicAdd(&aa[b * HW + idx], att);
    float* outp = out + (size_t)b * C * HW + idx;
#pragma unroll
    for (int c = 0; c < C; ++c) {
        atomicAdd(&outp[(size_t)c * HW], xv[c] * att);
    }
}

__global__ __launch_bounds__(256) void normalize_kernel(
    float* __restrict__ out, const float* __restrict__ aa)
{
    int i4 = blockIdx.x * 256 + threadIdx.x;
    size_t e = (size_t)i4 * 4;
    int b = (int)(e / ((size_t)C * HW));
    int p = (int)(e & (size_t)(HW - 1));
    float4 v = *reinterpret_cast<float4*>(out + e);
    const float4 a = *reinterpret_cast<const float4*>(aa + (size_t)b * HW + p);
    v.x /= a.x; v.y /= a.y; v.z /= a.z; v.w /= a.w;
    *reinterpret_cast<float4*>(out + e) = v;
}
} // namespace

extern "C" void kernel_launch(void* const* d_in, const int* in_sizes, int n_in,
                              void* d_out, int out_size, void* d_ws, size_t ws_size,
                              hipStream_t stream) {
    const float* x    = (const float*)d_in[0];
    const float* wmat = (const float*)d_in[1];
    const float* bias = (const float*)d_in[2];

    float* out    = (float*)d_out;                    // [B,C,H,W]
    float* offset = out + (size_t)B * C * HW;         // [B,2,H,W]
    float* dest   = offset + (size_t)B * 2 * HW;      // [B,2,H,W]

    // ws layout for the sort+gather path (~152 MB)
    char* w0 = (char*)d_ws;
    uint4* xwT   = (uint4*)w0;                                  // 128 MB
    float* att_a = (float*)(w0 + (size_t)ND * 128);             // 4 MB
    int*   idx_a = (int*)((char*)att_a + (size_t)ND * 4);       // 4 MB
    int*   count = (int*)((char*)idx_a + (size_t)ND * 4);       // 4 MB
    int*   ctrs  = (int*)((char*)count + (size_t)ND * 4);       // [alloc, heavy_n]
    int*   base  = (int*)((char*)ctrs + 256);                   // 4 MB
    int*   cursor= (int*)((char*)base + (size_t)ND * 4);        // 4 MB
    int*   slist = (int*)((char*)cursor + (size_t)ND * 4);      // 4 MB
    int*   heavy = (int*)((char*)slist + (size_t)ND * 4);       // 64 KB
    size_t need  = (size_t)(((char*)heavy + HEAVY_CAP * 4) - w0);

    if (ws_size >= need) {
        // zero count histogram + counters in one memset
        hipMemsetAsync(count, 0, (size_t)ND * 4 + 256, stream);
        conv_kernel<<<ND / 256, 256, 0, stream>>>(
            x, wmat, bias, xwT, att_a, idx_a, count, offset, dest);
        scan_alloc_kernel<<<ND / 256, 256, 0, stream>>>(count, base, cursor, &ctrs[0]);
        place_kernel<<<ND / 256, 256, 0, stream>>>(idx_a, cursor, slist);
        gather_kernel<<<ND / 256, 256, 0, stream>>>(
            xwT, att_a, count, base, slist, out, heavy, &ctrs[1]);
        heavy_kernel<<<512, 256, 0, stream>>>(
            (const unsigned short*)xwT, att_a, count, base, slist, out, heavy, &ctrs[1]);
    } else {
        // fallback: R1 path, accumulate directly in d_out (4 MB ws)
        float* aa = (float*)d_ws;
        hipMemsetAsync(out, 0, (size_t)B * C * HW * sizeof(float), stream);
        init_aa_kernel<<<B * HW / 256, 256, 0, stream>>>(aa);
        conv_scatter_kernel<<<B * HW / 256, 256, 0, stream>>>(
            x, wmat, bias, out, offset, dest, aa);
        normalize_kernel<<<(B * (size_t)C * HW / 4) / 256, 256, 0, stream>>>(out, aa);
    }
}

// Round 4
// 628.161 us; speedup vs baseline: 8.4583x; 1.2511x over previous
//
#include <hip/hip_runtime.h>

namespace {
constexpr int B = 4, C = 64, H = 512, W = 512;
constexpr int HW = H * W;                 // 2^18
constexpr int ND = B * HW;                // 2^20 sources == destinations
constexpr float EPS = 1e-5f;
constexpr int KT = 16;                    // heavy-destination threshold
constexpr int HEAVY_CAP = 65536;          // >= ND/(KT+1) = 61680, pigeonhole-safe

__device__ __forceinline__ float bf16_lo(unsigned int u) {
    return __uint_as_float(u << 16);
}
__device__ __forceinline__ float bf16_hi(unsigned int u) {
    return __uint_as_float(u & 0xffff0000u);
}
__device__ __forceinline__ unsigned int pack_bf16(float a, float b) {
    unsigned int ua = __float_as_uint(a), ub = __float_as_uint(b);
    ua = (ua + 0x7fffu + ((ua >> 16) & 1u)) >> 16;   // RNE f32->bf16
    ub = (ub + 0x7fffu + ((ub >> 16) & 1u)) >> 16;
    return ua | (ub << 16);
}

// ---------------- fast path: sort records, then stream-gather --------------

__global__ __launch_bounds__(256) void conv_kernel(
    const float* __restrict__ x, const float* __restrict__ wmat,
    const float* __restrict__ bias,
    float* __restrict__ att_a, int* __restrict__ idx_a,
    int* __restrict__ count,
    float* __restrict__ offset, float* __restrict__ dest)
{
    __shared__ float wsh[3 * C];
    int t = threadIdx.x;
    if (t < 3 * C) wsh[t] = wmat[t];
    __syncthreads();

    int gid = blockIdx.x * 256 + t;       // source id (b<<18 | p)
    int b = gid >> 18;
    int p = gid & (HW - 1);
    int hh = p >> 9, ww = p & (W - 1);

    const float* xb = x + (size_t)b * C * HW + p;
    float acc0 = 0.f, acc1 = 0.f, acc2 = 0.f;
#pragma unroll
    for (int c = 0; c < C; ++c) {
        float v = xb[(size_t)c * HW];     // coalesced per c
        acc0 = fmaf(v, wsh[c], acc0);
        acc1 = fmaf(v, wsh[C + c], acc1);
        acc2 = fmaf(v, wsh[2 * C + c], acc2);
    }
    acc0 += bias[0]; acc1 += bias[1]; acc2 += bias[2];

    float off_y = acc0 * (float)H;        // DOWNSAMPLE = 1.0
    float off_x = acc1 * (float)W;
    float att = expf(acc2);

    int dy = (int)rintf((float)hh + off_y);   // RNE == jnp.round
    dy = min(max(dy, 0), H - 1);
    int dx = (int)rintf((float)ww + off_x);
    dx = min(max(dx, 0), W - 1);
    int idx = dy * W + dx;

    size_t ob = (size_t)b * 2 * HW;
    offset[ob + p]      = off_y;
    offset[ob + HW + p] = off_x;
    dest[ob + p]      = (float)dy;
    dest[ob + HW + p] = (float)dx;

    att_a[gid] = att;
    idx_a[gid] = idx;
    atomicAdd(&count[(b << 18) | idx], 1);
}

__global__ __launch_bounds__(256) void scan_alloc_kernel(
    const int* __restrict__ count, int* __restrict__ base,
    int* __restrict__ cursor, int* __restrict__ alloc)
{
    __shared__ int sd[256];
    __shared__ int blockBase;
    int t = threadIdx.x;
    int i = blockIdx.x * 256 + t;
    int c = count[i];
    sd[t] = c;
    __syncthreads();
#pragma unroll
    for (int off = 1; off < 256; off <<= 1) {     // Hillis-Steele inclusive
        int v = (t >= off) ? sd[t - off] : 0;
        __syncthreads();
        sd[t] += v;
        __syncthreads();
    }
    if (t == 255) blockBase = atomicAdd(alloc, sd[255]);
    __syncthreads();
    int bb = blockBase + sd[t] - c;
    base[i] = bb;
    cursor[i] = bb;
}

// re-read x, premultiply, write bf16 record into its sorted CSR slot
__global__ __launch_bounds__(256) void sortcopy_kernel(
    const float* __restrict__ x, const float* __restrict__ att_a,
    const int* __restrict__ idx_a, int* __restrict__ cursor,
    uint4* __restrict__ rec, float* __restrict__ att_s)
{
    int s = blockIdx.x * 256 + threadIdx.x;
    int b = s >> 18;
    int p = s & (HW - 1);
    float att = att_a[s];
    int d = (s & ~(HW - 1)) | idx_a[s];
    int pos = atomicAdd(&cursor[d], 1);

    const float* xb = x + (size_t)b * C * HW + p;
    uint4* row = rec + (size_t)pos * 8;
#pragma unroll
    for (int j = 0; j < 8; ++j) {
        float v0 = xb[(size_t)(j * 8 + 0) * HW] * att;
        float v1 = xb[(size_t)(j * 8 + 1) * HW] * att;
        float v2 = xb[(size_t)(j * 8 + 2) * HW] * att;
        float v3 = xb[(size_t)(j * 8 + 3) * HW] * att;
        float v4 = xb[(size_t)(j * 8 + 4) * HW] * att;
        float v5 = xb[(size_t)(j * 8 + 5) * HW] * att;
        float v6 = xb[(size_t)(j * 8 + 6) * HW] * att;
        float v7 = xb[(size_t)(j * 8 + 7) * HW] * att;
        uint4 u;
        u.x = pack_bf16(v0, v1); u.y = pack_bf16(v2, v3);
        u.z = pack_bf16(v4, v5); u.w = pack_bf16(v6, v7);
        row[j] = u;                       // scattered 128B full-line write
    }
    att_s[pos] = att;
}

__global__ __launch_bounds__(256) void gather_kernel(
    const uint4* __restrict__ rec, const float* __restrict__ att_s,
    const int* __restrict__ count, const int* __restrict__ base,
    float* __restrict__ out, int* __restrict__ heavy, int* __restrict__ heavy_n)
{
    int d = blockIdx.x * 256 + threadIdx.x;
    int k = count[d];
    if (k > KT) {
        heavy[atomicAdd(heavy_n, 1)] = d;
        return;
    }
    float acc[C];
#pragma unroll
    for (int c = 0; c < C; ++c) acc[c] = 0.f;
    float asum = 0.f;
    int st = base[d];
    for (int i = 0; i < k; ++i) {
        asum += att_s[st + i];
        const uint4* row = rec + (size_t)(st + i) * 8;   // sequential records
#pragma unroll
        for (int j = 0; j < 8; ++j) {
            uint4 v = row[j];
            acc[j * 8 + 0] += bf16_lo(v.x); acc[j * 8 + 1] += bf16_hi(v.x);
            acc[j * 8 + 2] += bf16_lo(v.y); acc[j * 8 + 3] += bf16_hi(v.y);
            acc[j * 8 + 4] += bf16_lo(v.z); acc[j * 8 + 5] += bf16_hi(v.z);
            acc[j * 8 + 6] += bf16_lo(v.w); acc[j * 8 + 7] += bf16_hi(v.w);
        }
    }
    float rinv = 1.0f / (EPS + asum);
    int b = d >> 18, p = d & (HW - 1);
    float* op = out + (size_t)b * C * HW + p;
#pragma unroll
    for (int c = 0; c < C; ++c) op[(size_t)c * HW] = acc[c] * rinv;  // coalesced
}

__global__ __launch_bounds__(256) void heavy_kernel(
    const unsigned short* __restrict__ rec16, const float* __restrict__ att_s,
    const int* __restrict__ count, const int* __restrict__ base,
    float* __restrict__ out,
    const int* __restrict__ heavy, const int* __restrict__ heavy_n)
{
    __shared__ float red[4][C];
    __shared__ float asums[4];
    int nh = *heavy_n;
    int wid = threadIdx.x >> 6, lane = threadIdx.x & 63;
    for (int hi = blockIdx.x; hi < nh; hi += gridDim.x) {
        int d = heavy[hi];
        int k = count[d], st = base[d];
        float acc = 0.f, asum = 0.f;
        for (int i = wid; i < k; i += 4) {
            asum += att_s[st + i];
            unsigned short u = rec16[(size_t)(st + i) * 64 + lane];  // coalesced
            acc += __uint_as_float(((unsigned int)u) << 16);
        }
        red[wid][lane] = acc;
        if (lane == 0) asums[wid] = asum;
        __syncthreads();
        if (wid == 0) {
            float a = red[0][lane] + red[1][lane] + red[2][lane] + red[3][lane];
            float as = asums[0] + asums[1] + asums[2] + asums[3];
            int b = d >> 18, p = d & (HW - 1);
            out[(size_t)b * C * HW + (size_t)lane * HW + p] = a / (EPS + as);
        }
        __syncthreads();
    }
}

// ---------------- fallback path (R1, needs only 4 MB ws) ----------------

__global__ __launch_bounds__(256) void init_aa_kernel(float* __restrict__ aa) {
    int i = blockIdx.x * 256 + threadIdx.x;
    aa[i] = EPS;
}

__global__ __launch_bounds__(256) void conv_scatter_kernel(
    const float* __restrict__ x, const float* __restrict__ wmat,
    const float* __restrict__ bias, float* __restrict__ out,
    float* __restrict__ offset, float* __restrict__ dest,
    float* __restrict__ aa)
{
    __shared__ float wsh[3 * C];
    int t = threadIdx.x;
    if (t < 3 * C) wsh[t] = wmat[t];
    __syncthreads();

    int gid = blockIdx.x * 256 + t;
    int b = gid >> 18;
    int p = gid & (HW - 1);
    int hh = p >> 9, ww = p & (W - 1);

    const float* xb = x + (size_t)b * C * HW + p;
    float xv[C];
    float acc0 = 0.f, acc1 = 0.f, acc2 = 0.f;
#pragma unroll
    for (int c = 0; c < C; ++c) {
        float v = xb[(size_t)c * HW];
        xv[c] = v;
        acc0 = fmaf(v, wsh[c], acc0);
        acc1 = fmaf(v, wsh[C + c], acc1);
        acc2 = fmaf(v, wsh[2 * C + c], acc2);
    }
    acc0 += bias[0]; acc1 += bias[1]; acc2 += bias[2];

    float off_y = acc0 * (float)H;
    float off_x = acc1 * (float)W;
    float att = expf(acc2);

    int dy = (int)rintf((float)hh + off_y);
    dy = min(max(dy, 0), H - 1);
    int dx = (int)rintf((float)ww + off_x);
    dx = min(max(dx, 0), W - 1);
    int idx = dy * W + dx;

    size_t ob = (size_t)b * 2 * HW;
    offset[ob + p]      = off_y;
    offset[ob + HW + p] = off_x;
    dest[ob + p]      = (float)dy;
    dest[ob + HW + p] = (float)dx;

    atomicAdd(&aa[b * HW + idx], att);
    float* outp = out + (size_t)b * C * HW + idx;
#pragma unroll
    for (int c = 0; c < C; ++c) {
        atomicAdd(&outp[(size_t)c * HW], xv[c] * att);
    }
}

__global__ __launch_bounds__(256) void normalize_kernel(
    float* __restrict__ out, const float* __restrict__ aa)
{
    int i4 = blockIdx.x * 256 + threadIdx.x;
    size_t e = (size_t)i4 * 4;
    int b = (int)(e / ((size_t)C * HW));
    int p = (int)(e & (size_t)(HW - 1));
    float4 v = *reinterpret_cast<float4*>(out + e);
    const float4 a = *reinterpret_cast<const float4*>(aa + (size_t)b * HW + p);
    v.x /= a.x; v.y /= a.y; v.z /= a.z; v.w /= a.w;
    *reinterpret_cast<float4*>(out + e) = v;
}
} // namespace

extern "C" void kernel_launch(void* const* d_in, const int* in_sizes, int n_in,
                              void* d_out, int out_size, void* d_ws, size_t ws_size,
                              hipStream_t stream) {
    const float* x    = (const float*)d_in[0];
    const float* wmat = (const float*)d_in[1];
    const float* bias = (const float*)d_in[2];

    float* out    = (float*)d_out;                    // [B,C,H,W]
    float* offset = out + (size_t)B * C * HW;         // [B,2,H,W]
    float* dest   = offset + (size_t)B * 2 * HW;      // [B,2,H,W]

    // ws layout (~152.3 MB)
    char* w0 = (char*)d_ws;
    uint4* rec   = (uint4*)w0;                                  // 128 MB sorted records
    float* att_a = (float*)(w0 + (size_t)ND * 128);             // 4 MB
    float* att_s = (float*)((char*)att_a + (size_t)ND * 4);     // 4 MB sorted att
    int*   idx_a = (int*)((char*)att_s + (size_t)ND * 4);       // 4 MB
    int*   count = (int*)((char*)idx_a + (size_t)ND * 4);       // 4 MB
    int*   ctrs  = (int*)((char*)count + (size_t)ND * 4);       // [alloc, heavy_n]
    int*   base  = (int*)((char*)ctrs + 256);                   // 4 MB
    int*   cursor= (int*)((char*)base + (size_t)ND * 4);        // 4 MB
    int*   heavy = (int*)((char*)cursor + (size_t)ND * 4);      // 256 KB
    size_t need  = (size_t)(((char*)heavy + HEAVY_CAP * 4) - w0);

    if (ws_size >= need) {
        hipMemsetAsync(count, 0, (size_t)ND * 4 + 256, stream);  // count + ctrs
        conv_kernel<<<ND / 256, 256, 0, stream>>>(
            x, wmat, bias, att_a, idx_a, count, offset, dest);
        scan_alloc_kernel<<<ND / 256, 256, 0, stream>>>(count, base, cursor, &ctrs[0]);
        sortcopy_kernel<<<ND / 256, 256, 0, stream>>>(
            x, att_a, idx_a, cursor, rec, att_s);
        gather_kernel<<<ND / 256, 256, 0, stream>>>(
            rec, att_s, count, base, out, heavy, &ctrs[1]);
        heavy_kernel<<<1024, 256, 0, stream>>>(
            (const unsigned short*)rec, att_s, count, base, out, heavy, &ctrs[1]);
    } else {
        // fallback: R1 path (4 MB ws)
        float* aa = (float*)d_ws;
        hipMemsetAsync(out, 0, (size_t)B * C * HW * sizeof(float), stream);
        init_aa_kernel<<<B * HW / 256, 256, 0, stream>>>(aa);
        conv_scatter_kernel<<<B * HW / 256, 256, 0, stream>>>(
            x, wmat, bias, out, offset, dest, aa);
        normalize_kernel<<<(B * (size_t)C * HW / 4) / 256, 256, 0, stream>>>(out, aa);
    }
}

// Round 5
// 565.242 us; speedup vs baseline: 9.3998x; 1.1113x over previous
//
#include <hip/hip_runtime.h>

namespace {
constexpr int B = 4, C = 64, H = 512, W = 512;
constexpr int HW = H * W;                 // 2^18
constexpr int ND = B * HW;                // 2^20 sources == destinations
constexpr float EPS = 1e-5f;
constexpr int KT = 16;                    // heavy-destination threshold
constexpr int HEAVY_CAP = 65536;          // >= ND/(KT+1) = 61680, pigeonhole-safe

__device__ __forceinline__ float bf16_lo(unsigned int u) {
    return __uint_as_float(u << 16);
}
__device__ __forceinline__ float bf16_hi(unsigned int u) {
    return __uint_as_float(u & 0xffff0000u);
}
__device__ __forceinline__ unsigned int pack_bf16(float a, float b) {
    unsigned int ua = __float_as_uint(a), ub = __float_as_uint(b);
    ua = (ua + 0x7fffu + ((ua >> 16) & 1u)) >> 16;   // RNE f32->bf16
    ub = (ub + 0x7fffu + ((ub >> 16) & 1u)) >> 16;
    return ua | (ub << 16);
}

// ---------------- fast path: sort records, then stream-gather --------------

__global__ __launch_bounds__(256) void conv_kernel(
    const float* __restrict__ x, const float* __restrict__ wmat,
    const float* __restrict__ bias,
    float* __restrict__ att_a, int* __restrict__ idx_a,
    int* __restrict__ count,
    float* __restrict__ offset, float* __restrict__ dest)
{
    __shared__ float wsh[3 * C];
    int t = threadIdx.x;
    if (t < 3 * C) wsh[t] = wmat[t];
    __syncthreads();

    int gid = blockIdx.x * 256 + t;       // source id (b<<18 | p)
    int b = gid >> 18;
    int p = gid & (HW - 1);
    int hh = p >> 9, ww = p & (W - 1);

    const float* xb = x + (size_t)b * C * HW + p;
    float acc0 = 0.f, acc1 = 0.f, acc2 = 0.f;
#pragma unroll
    for (int c = 0; c < C; ++c) {
        float v = xb[(size_t)c * HW];     // coalesced per c
        acc0 = fmaf(v, wsh[c], acc0);
        acc1 = fmaf(v, wsh[C + c], acc1);
        acc2 = fmaf(v, wsh[2 * C + c], acc2);
    }
    acc0 += bias[0]; acc1 += bias[1]; acc2 += bias[2];

    float off_y = acc0 * (float)H;        // DOWNSAMPLE = 1.0
    float off_x = acc1 * (float)W;
    float att = expf(acc2);

    int dy = (int)rintf((float)hh + off_y);   // RNE == jnp.round
    dy = min(max(dy, 0), H - 1);
    int dx = (int)rintf((float)ww + off_x);
    dx = min(max(dx, 0), W - 1);
    int idx = dy * W + dx;

    size_t ob = (size_t)b * 2 * HW;
    offset[ob + p]      = off_y;
    offset[ob + HW + p] = off_x;
    dest[ob + p]      = (float)dy;
    dest[ob + HW + p] = (float)dx;

    att_a[gid] = att;
    idx_a[gid] = idx;
    atomicAdd(&count[(b << 18) | idx], 1);
}

__global__ __launch_bounds__(256) void scan_alloc_kernel(
    const int* __restrict__ count, int* __restrict__ base,
    int* __restrict__ cursor, int* __restrict__ alloc)
{
    __shared__ int sd[256];
    __shared__ int blockBase;
    int t = threadIdx.x;
    int i = blockIdx.x * 256 + t;
    int c = count[i];
    sd[t] = c;
    __syncthreads();
#pragma unroll
    for (int off = 1; off < 256; off <<= 1) {     // Hillis-Steele inclusive
        int v = (t >= off) ? sd[t - off] : 0;
        __syncthreads();
        sd[t] += v;
        __syncthreads();
    }
    if (t == 255) blockBase = atomicAdd(alloc, sd[255]);
    __syncthreads();
    int bb = blockBase + sd[t] - c;
    base[i] = bb;
    cursor[i] = bb;
}

// re-read x, premultiply, write bf16 record into its sorted CSR slot
__global__ __launch_bounds__(256) void sortcopy_kernel(
    const float* __restrict__ x, const float* __restrict__ att_a,
    const int* __restrict__ idx_a, int* __restrict__ cursor,
    uint4* __restrict__ rec, float* __restrict__ att_s)
{
    int s = blockIdx.x * 256 + threadIdx.x;
    int b = s >> 18;
    int p = s & (HW - 1);
    float att = att_a[s];
    int d = (s & ~(HW - 1)) | idx_a[s];
    int pos = atomicAdd(&cursor[d], 1);

    const float* xb = x + (size_t)b * C * HW + p;
    uint4* row = rec + (size_t)pos * 8;
#pragma unroll
    for (int j = 0; j < 8; ++j) {
        float v0 = xb[(size_t)(j * 8 + 0) * HW] * att;
        float v1 = xb[(size_t)(j * 8 + 1) * HW] * att;
        float v2 = xb[(size_t)(j * 8 + 2) * HW] * att;
        float v3 = xb[(size_t)(j * 8 + 3) * HW] * att;
        float v4 = xb[(size_t)(j * 8 + 4) * HW] * att;
        float v5 = xb[(size_t)(j * 8 + 5) * HW] * att;
        float v6 = xb[(size_t)(j * 8 + 6) * HW] * att;
        float v7 = xb[(size_t)(j * 8 + 7) * HW] * att;
        uint4 u;
        u.x = pack_bf16(v0, v1); u.y = pack_bf16(v2, v3);
        u.z = pack_bf16(v4, v5); u.w = pack_bf16(v6, v7);
        row[j] = u;                       // 128B contiguous record per thread
    }
    att_s[pos] = att;
}

__global__ __launch_bounds__(256) void gather_kernel(
    const uint4* __restrict__ rec, const float* __restrict__ att_s,
    const int* __restrict__ count, const int* __restrict__ base,
    float* __restrict__ out, int* __restrict__ heavy, int* __restrict__ heavy_n)
{
    int d = blockIdx.x * 256 + threadIdx.x;
    int k = count[d];
    if (k > KT) {
        heavy[atomicAdd(heavy_n, 1)] = d;
        return;
    }
    float acc[C];
#pragma unroll
    for (int c = 0; c < C; ++c) acc[c] = 0.f;
    float asum = 0.f;
    int st = base[d];
    for (int i = 0; i < k; ++i) {
        asum += att_s[st + i];
        const uint4* row = rec + (size_t)(st + i) * 8;   // sequential records
#pragma unroll
        for (int j = 0; j < 8; ++j) {
            uint4 v = row[j];
            acc[j * 8 + 0] += bf16_lo(v.x); acc[j * 8 + 1] += bf16_hi(v.x);
            acc[j * 8 + 2] += bf16_lo(v.y); acc[j * 8 + 3] += bf16_hi(v.y);
            acc[j * 8 + 4] += bf16_lo(v.z); acc[j * 8 + 5] += bf16_hi(v.z);
            acc[j * 8 + 6] += bf16_lo(v.w); acc[j * 8 + 7] += bf16_hi(v.w);
        }
    }
    float rinv = 1.0f / (EPS + asum);
    int b = d >> 18, p = d & (HW - 1);
    float* op = out + (size_t)b * C * HW + p;
#pragma unroll
    for (int c = 0; c < C; ++c) op[(size_t)c * HW] = acc[c] * rinv;  // coalesced
}

// one WAVE per heavy destination; 8 records (1KB) per wave-iteration
__global__ __launch_bounds__(256) void heavy_kernel(
    const uint4* __restrict__ rec, const float* __restrict__ att_s,
    const int* __restrict__ count, const int* __restrict__ base,
    float* __restrict__ out,
    const int* __restrict__ heavy, const int* __restrict__ heavy_n)
{
    int nh = *heavy_n;
    int gw = (blockIdx.x * 256 + threadIdx.x) >> 6;   // global wave id
    int lane = threadIdx.x & 63;
    int nwaves = gridDim.x * 4;
    int rgrp = lane >> 3;                 // record-in-group 0..7
    int q = lane & 7;                     // channel-group 0..7

    for (int hi = gw; hi < nh; hi += nwaves) {
        int d = heavy[hi];
        int k = count[d], st = base[d];

        float asum = 0.f;
        for (int i = lane; i < k; i += 64) asum += att_s[st + i];
#pragma unroll
        for (int m = 32; m; m >>= 1) asum += __shfl_xor(asum, m, 64);

        float acc[8];
#pragma unroll
        for (int j = 0; j < 8; ++j) acc[j] = 0.f;
        const uint4* rp = rec + (size_t)st * 8 + lane;
        int nit = (k + 7) >> 3;
        for (int it = 0; it < nit; ++it) {
            int r = it * 8 + rgrp;
            if (r < k) {
                uint4 v = rp[(size_t)it * 64];    // lane-coalesced 1KB/wave
                acc[0] += bf16_lo(v.x); acc[1] += bf16_hi(v.x);
                acc[2] += bf16_lo(v.y); acc[3] += bf16_hi(v.y);
                acc[4] += bf16_lo(v.z); acc[5] += bf16_hi(v.z);
                acc[6] += bf16_lo(v.w); acc[7] += bf16_hi(v.w);
            }
        }
        // reduce across the 8 record-groups (lane bits 3..5); channel-group preserved
#pragma unroll
        for (int m = 8; m < 64; m <<= 1) {
#pragma unroll
            for (int j = 0; j < 8; ++j) acc[j] += __shfl_xor(acc[j], m, 64);
        }
        if (lane < 8) {                   // lane q=lane writes channels lane*8..+7
            float rinv = 1.0f / (EPS + asum);
            int b = d >> 18, p = d & (HW - 1);
            float* op = out + (size_t)b * C * HW + (size_t)(lane * 8) * HW + p;
#pragma unroll
            for (int j = 0; j < 8; ++j) op[(size_t)j * HW] = acc[j] * rinv;
        }
    }
}

// ---------------- fallback path (R1, needs only 4 MB ws) ----------------

__global__ __launch_bounds__(256) void init_aa_kernel(float* __restrict__ aa) {
    int i = blockIdx.x * 256 + threadIdx.x;
    aa[i] = EPS;
}

__global__ __launch_bounds__(256) void conv_scatter_kernel(
    const float* __restrict__ x, const float* __restrict__ wmat,
    const float* __restrict__ bias, float* __restrict__ out,
    float* __restrict__ offset, float* __restrict__ dest,
    float* __restrict__ aa)
{
    __shared__ float wsh[3 * C];
    int t = threadIdx.x;
    if (t < 3 * C) wsh[t] = wmat[t];
    __syncthreads();

    int gid = blockIdx.x * 256 + t;
    int b = gid >> 18;
    int p = gid & (HW - 1);
    int hh = p >> 9, ww = p & (W - 1);

    const float* xb = x + (size_t)b * C * HW + p;
    float xv[C];
    float acc0 = 0.f, acc1 = 0.f, acc2 = 0.f;
#pragma unroll
    for (int c = 0; c < C; ++c) {
        float v = xb[(size_t)c * HW];
        xv[c] = v;
        acc0 = fmaf(v, wsh[c], acc0);
        acc1 = fmaf(v, wsh[C + c], acc1);
        acc2 = fmaf(v, wsh[2 * C + c], acc2);
    }
    acc0 += bias[0]; acc1 += bias[1]; acc2 += bias[2];

    float off_y = acc0 * (float)H;
    float off_x = acc1 * (float)W;
    float att = expf(acc2);

    int dy = (int)rintf((float)hh + off_y);
    dy = min(max(dy, 0), H - 1);
    int dx = (int)rintf((float)ww + off_x);
    dx = min(max(dx, 0), W - 1);
    int idx = dy * W + dx;

    size_t ob = (size_t)b * 2 * HW;
    offset[ob + p]      = off_y;
    offset[ob + HW + p] = off_x;
    dest[ob + p]      = (float)dy;
    dest[ob + HW + p] = (float)dx;

    atomicAdd(&aa[b * HW + idx], att);
    float* outp = out + (size_t)b * C * HW + idx;
#pragma unroll
    for (int c = 0; c < C; ++c) {
        atomicAdd(&outp[(size_t)c * HW], xv[c] * att);
    }
}

__global__ __launch_bounds__(256) void normalize_kernel(
    float* __restrict__ out, const float* __restrict__ aa)
{
    int i4 = blockIdx.x * 256 + threadIdx.x;
    size_t e = (size_t)i4 * 4;
    int b = (int)(e / ((size_t)C * HW));
    int p = (int)(e & (size_t)(HW - 1));
    float4 v = *reinterpret_cast<float4*>(out + e);
    const float4 a = *reinterpret_cast<const float4*>(aa + (size_t)b * HW + p);
    v.x /= a.x; v.y /= a.y; v.z /= a.z; v.w /= a.w;
    *reinterpret_cast<float4*>(out + e) = v;
}
} // namespace

extern "C" void kernel_launch(void* const* d_in, const int* in_sizes, int n_in,
                              void* d_out, int out_size, void* d_ws, size_t ws_size,
                              hipStream_t stream) {
    const float* x    = (const float*)d_in[0];
    const float* wmat = (const float*)d_in[1];
    const float* bias = (const float*)d_in[2];

    float* out    = (float*)d_out;                    // [B,C,H,W]
    float* offset = out + (size_t)B * C * HW;         // [B,2,H,W]
    float* dest   = offset + (size_t)B * 2 * HW;      // [B,2,H,W]

    // ws layout (~152.3 MB)
    char* w0 = (char*)d_ws;
    uint4* rec   = (uint4*)w0;                                  // 128 MB sorted records
    float* att_a = (float*)(w0 + (size_t)ND * 128);             // 4 MB
    float* att_s = (float*)((char*)att_a + (size_t)ND * 4);     // 4 MB sorted att
    int*   idx_a = (int*)((char*)att_s + (size_t)ND * 4);       // 4 MB
    int*   count = (int*)((char*)idx_a + (size_t)ND * 4);       // 4 MB
    int*   ctrs  = (int*)((char*)count + (size_t)ND * 4);       // [alloc, heavy_n]
    int*   base  = (int*)((char*)ctrs + 256);                   // 4 MB
    int*   cursor= (int*)((char*)base + (size_t)ND * 4);        // 4 MB
    int*   heavy = (int*)((char*)cursor + (size_t)ND * 4);      // 256 KB
    size_t need  = (size_t)(((char*)heavy + HEAVY_CAP * 4) - w0);

    if (ws_size >= need) {
        hipMemsetAsync(count, 0, (size_t)ND * 4 + 256, stream);  // count + ctrs
        conv_kernel<<<ND / 256, 256, 0, stream>>>(
            x, wmat, bias, att_a, idx_a, count, offset, dest);
        scan_alloc_kernel<<<ND / 256, 256, 0, stream>>>(count, base, cursor, &ctrs[0]);
        sortcopy_kernel<<<ND / 256, 256, 0, stream>>>(
            x, att_a, idx_a, cursor, rec, att_s);
        gather_kernel<<<ND / 256, 256, 0, stream>>>(
            rec, att_s, count, base, out, heavy, &ctrs[1]);
        heavy_kernel<<<4096, 256, 0, stream>>>(
            rec, att_s, count, base, out, heavy, &ctrs[1]);
    } else {
        // fallback: R1 path (4 MB ws)
        float* aa = (float*)d_ws;
        hipMemsetAsync(out, 0, (size_t)B * C * HW * sizeof(float), stream);
        init_aa_kernel<<<B * HW / 256, 256, 0, stream>>>(aa);
        conv_scatter_kernel<<<B * HW / 256, 256, 0, stream>>>(
            x, wmat, bias, out, offset, dest, aa);
        normalize_kernel<<<(B * (size_t)C * HW / 4) / 256, 256, 0, stream>>>(out, aa);
    }
}